// Round 7
// baseline (486.121 us; speedup 1.0000x reference)
//
#include <hip/hip_runtime.h>
#include <math.h>

#define QMAXF 127.0f

struct Ptrs4 { const float* p[4]; };

__device__ __forceinline__ float qscale(float m) {
    // scale = where(max_abs > 0, max_abs/127, 1.0)
    return (m > 0.0f) ? (m / QMAXF) : 1.0f;
}

__device__ __forceinline__ float quant1(float x, float s) {
    // clip(round(x/s), -127, 127) * s   (round = half-to-even, matches jnp.round)
    float r = rintf(x / s);
    r = fminf(fmaxf(r, -QMAXF), QMAXF);
    return r * s;
}

// Block-wide max over all threads' v. All threads must call. sred must hold >=17 floats.
__device__ __forceinline__ float block_max_red(float v, float* sred) {
    #pragma unroll
    for (int off = 32; off > 0; off >>= 1)
        v = fmaxf(v, __shfl_down(v, off, 64));
    int wave = threadIdx.x >> 6;
    int lane = threadIdx.x & 63;
    __syncthreads();                 // protect sred reuse across calls
    if (lane == 0) sred[wave] = v;
    __syncthreads();
    if (threadIdx.x == 0) {
        int nw = blockDim.x >> 6;
        float m = sred[0];
        for (int i = 1; i < nw; ++i) m = fmaxf(m, sred[i]);
        sred[16] = m;
    }
    __syncthreads();
    return sred[16];
}

// Per-tensor quantize of the 4 values each thread holds (tensor = 4096 elems across block).
__device__ __forceinline__ void quant_vec4(float* a, float* sred) {
    float pm = 0.0f;
    #pragma unroll
    for (int i = 0; i < 4; ++i) pm = fmaxf(pm, fabsf(a[i]));
    float s = qscale(block_max_red(pm, sred));
    #pragma unroll
    for (int i = 0; i < 4; ++i) a[i] = quant1(a[i], s);
}

// ---------------------------------------------------------------------------
// Kernel 1: quantize concat = Q([h, x]) (block 0) and the 4 biases (blocks 1-4).
// Also zeroes the 4 atomic-max slots (ws is poisoned 0xAA before each launch).
// ---------------------------------------------------------------------------
__global__ __launch_bounds__(1024) void k_prep(
    const float* __restrict__ x, const float* __restrict__ h,
    Ptrs4 biases, float* __restrict__ concat_q, float* __restrict__ qb,
    unsigned* __restrict__ gmax)
{
    __shared__ float sred[17];
    int tid = threadIdx.x;
    if (blockIdx.x == 0) {
        if (tid < 4) gmax[tid] = 0u;
        float vals[8];
        float pm = 0.0f;
        #pragma unroll
        for (int i = 0; i < 8; ++i) {
            int idx = i * 1024 + tid;               // 0..8191
            float v = (i < 4) ? h[idx] : x[idx - 4096];  // concat = [h, inputs]
            vals[i] = v;
            pm = fmaxf(pm, fabsf(v));
        }
        float s = qscale(block_max_red(pm, sred));
        #pragma unroll
        for (int i = 0; i < 8; ++i) concat_q[i * 1024 + tid] = quant1(vals[i], s);
    } else {
        int g = blockIdx.x - 1;
        const float* __restrict__ b = biases.p[g];
        float vals[4];
        float pm = 0.0f;
        #pragma unroll
        for (int i = 0; i < 4; ++i) {
            float v = b[i * 1024 + tid];
            vals[i] = v;
            pm = fmaxf(pm, fabsf(v));
        }
        float s = qscale(block_max_red(pm, sred));
        #pragma unroll
        for (int i = 0; i < 4; ++i) qb[g * 4096 + i * 1024 + tid] = quant1(vals[i], s);
    }
}

// ---------------------------------------------------------------------------
// Kernel 2 (PRIMARY): ROW-TILED GEMV partials.
// Rounds 0-6 post-mortem: column-tiled variants (1-KB wave runs, 16-KB row
// stride, XCD = ct) all pinned at 3.4 TB/s regardless of pipeline depth
// (depth-1 round 0 == depth-12 round 6) -> depth was never the limit; the
// strided, XCD-scattered pattern is the remaining suspect (m13 contiguous
// copy hits 6.3 TB/s on this chip).
// New geometry: block = one (32-row x 4096-col) chunk of one gate.
//   grid (256 chunks, 4 gates) x 256 thr (4 waves), 16 waves/CU.
//   wave w owns cols [1024w, 1024w+1024); lane l: 4 float4s at
//   cols 1024w + 256j + 4l  -> each load is a unit-stride 1-KB wave
//   transaction; the 4 loads cover a contiguous 4-KB quarter-row; the
//   block sweeps 32 consecutive rows = 512 KB contiguous.
//   x chunk in LDS (lgkm; vmcnt stream stays pure weights).
// Per-column k-order: r ascending within chunk; chunks summed ascending in
// k_mid/k_reduce. (Tree differs from the old 32x256 split; the post-quant
// comparison absorbs ulp-level reassociation - jax's own matmul tree
// already differs and absmax was 0.0.)
// ---------------------------------------------------------------------------
__global__ __launch_bounds__(256, 4) void k_gemv_rows(
    Ptrs4 wts, const float* __restrict__ xq, float* __restrict__ partials)
{
    __shared__ float x_s[32];
    int chunk = blockIdx.x;   // 0..255   (rows chunk*32 .. +31)
    int g     = blockIdx.y;   // 0..3
    int tid   = threadIdx.x;
    int wave  = tid >> 6;
    int lane  = tid & 63;
    int r0    = chunk * 32;

    if (tid < 32) x_s[tid] = xq[r0 + tid];
    __syncthreads();

    int colbase = wave * 1024 + lane * 4;
    const float* __restrict__ wp = wts.p[g] + (size_t)r0 * 4096 + colbase;

    float4 a0 = {0.f,0.f,0.f,0.f}, a1 = {0.f,0.f,0.f,0.f};
    float4 a2 = {0.f,0.f,0.f,0.f}, a3 = {0.f,0.f,0.f,0.f};

    #pragma unroll
    for (int r = 0; r < 32; ++r) {
        const float* rp = wp + (size_t)r * 4096;
        float xv = x_s[r];
        float4 w0 = *(const float4*)(rp);
        float4 w1 = *(const float4*)(rp + 256);
        float4 w2 = *(const float4*)(rp + 512);
        float4 w3 = *(const float4*)(rp + 768);
        a0.x = fmaf(xv, w0.x, a0.x); a0.y = fmaf(xv, w0.y, a0.y);
        a0.z = fmaf(xv, w0.z, a0.z); a0.w = fmaf(xv, w0.w, a0.w);
        a1.x = fmaf(xv, w1.x, a1.x); a1.y = fmaf(xv, w1.y, a1.y);
        a1.z = fmaf(xv, w1.z, a1.z); a1.w = fmaf(xv, w1.w, a1.w);
        a2.x = fmaf(xv, w2.x, a2.x); a2.y = fmaf(xv, w2.y, a2.y);
        a2.z = fmaf(xv, w2.z, a2.z); a2.w = fmaf(xv, w2.w, a2.w);
        a3.x = fmaf(xv, w3.x, a3.x); a3.y = fmaf(xv, w3.y, a3.y);
        a3.z = fmaf(xv, w3.z, a3.z); a3.w = fmaf(xv, w3.w, a3.w);
    }

    float* out = partials + (size_t)(g * 256 + chunk) * 4096 + colbase;
    *(float4*)(out)       = a0;
    *(float4*)(out + 256) = a1;
    *(float4*)(out + 512) = a2;
    *(float4*)(out + 768) = a3;
}

// ---------------------------------------------------------------------------
// Kernel 2b (PRIMARY): funnel 256 row-chunks -> 32 (8:1, ascending), emitting
// the exact partials layout k_reduce already consumes.
// grid (4 colblocks, 32 s, 4 gates) x 256 thr; thread = 4 cols (float4).
// ---------------------------------------------------------------------------
__global__ __launch_bounds__(256) void k_mid(
    const float* __restrict__ pbig, float* __restrict__ psmall)
{
    int cb = blockIdx.x, s = blockIdx.y, g = blockIdx.z;
    int col = cb * 1024 + threadIdx.x * 4;
    const float* __restrict__ base = pbig + (size_t)(g * 256 + s * 8) * 4096 + col;
    float4 acc = *(const float4*)(base);
    #pragma unroll
    for (int j = 1; j < 8; ++j) {
        float4 v = *(const float4*)(base + (size_t)j * 4096);
        acc.x += v.x; acc.y += v.y; acc.z += v.z; acc.w += v.w;
    }
    *(float4*)(psmall + (size_t)(g * 32 + s) * 4096 + col) = acc;
}

// ---------------------------------------------------------------------------
// Kernel 2 (FALLBACK, ws too small): round-6 ring-buffered column-tiled GEMV.
// Known-passing at ~155 us.
// ---------------------------------------------------------------------------
__global__ __launch_bounds__(256, 2) void k_gemv_fb(
    Ptrs4 wts, const float* __restrict__ xq, float* __restrict__ partials)
{
    __shared__ float ring[4][8 * 512];
    __shared__ float x_s[256];

    int ct = blockIdx.x, kc = blockIdx.y, g = blockIdx.z;
    const float* __restrict__ W = wts.p[g];
    int tid  = threadIdx.x;
    int wave = tid >> 6;
    int lane = tid & 63;
    int k0 = kc * 256;
    const float* __restrict__ wbase = W + (size_t)k0 * 4096 + ct * 512;

    auto stage = [&](int st) {
        const float* wsrc = wbase + (size_t)(st * 8) * 4096;
        float* lbuf = &ring[st & 3][0];
        #pragma unroll
        for (int j = 0; j < 4; ++j) {
            int t = wave * 4 + j;
            int row = t >> 1, half = t & 1;
            __builtin_amdgcn_global_load_lds(
                (const __attribute__((address_space(1))) void*)
                    (wsrc + (size_t)row * 4096 + half * 256 + lane * 4),
                (__attribute__((address_space(3))) void*)
                    (lbuf + row * 512 + half * 256), 16, 0, 0);
        }
    };

    float ax = 0.f, ay = 0.f;
    auto compute = [&](int t) {
        const float* sl = &ring[t & 3][0];
        int kb = t * 8;
        #pragma unroll
        for (int r = 0; r < 8; ++r) {
            float xv = x_s[kb + r];
            float2 wv = *(const float2*)&sl[r * 512 + tid * 2];
            ax = fmaf(xv, wv.x, ax);
            ay = fmaf(xv, wv.y, ay);
        }
    };

    #define WAITBAR(N) asm volatile("s_waitcnt vmcnt(" #N ") lgkmcnt(0)\ns_barrier" ::: "memory")
    x_s[tid] = xq[k0 + tid];
    __syncthreads();
    stage(0); stage(1); stage(2);
    for (int t = 0; t < 30; ++t) {
        WAITBAR(8);
        compute(t);
        if (t + 3 < 32) stage(t + 3);
    }
    WAITBAR(4);
    compute(30);
    WAITBAR(0);
    compute(31);
    #undef WAITBAR

    int col0 = ct * 512 + tid * 2;
    float2 r; r.x = ax; r.y = ay;
    *(float2*)(partials + (size_t)(g * 32 + kc) * 4096 + col0) = r;
}

// ---------------------------------------------------------------------------
// Kernel 3: reduce 32 k-chunk partials per column; per-gate max|y| via atomicMax.
// grid = 64 blocks (gate = b>>4, colblock = b&15), block = 256.
// ---------------------------------------------------------------------------
__global__ __launch_bounds__(256) void k_reduce(
    const float* __restrict__ partials, float* __restrict__ y,
    unsigned* __restrict__ gmax)
{
    int g  = blockIdx.x >> 4;
    int cb = blockIdx.x & 15;
    int col = cb * 256 + threadIdx.x;
    float s = 0.0f;
    #pragma unroll 8
    for (int kc = 0; kc < 32; ++kc)
        s += partials[(size_t)(g * 32 + kc) * 4096 + col];
    y[g * 4096 + col] = s;

    float m = fabsf(s);
    #pragma unroll
    for (int off = 32; off > 0; off >>= 1)
        m = fmaxf(m, __shfl_down(m, off, 64));
    __shared__ float sm[4];
    int wave = threadIdx.x >> 6, lane = threadIdx.x & 63;
    if (lane == 0) sm[wave] = m;
    __syncthreads();
    if (threadIdx.x == 0) {
        float mm = fmaxf(fmaxf(sm[0], sm[1]), fmaxf(sm[2], sm[3]));
        atomicMax(gmax + g, __float_as_uint(mm));  // |y| >= 0: uint order == float order
    }
}

// ---------------------------------------------------------------------------
// Kernel 4: full quantized LSTM epilogue on one block (1024 thr x 4 elems/gate).
// gates: 0=f, 1=i, 2=c(candidate, tanh), 3=o
// ---------------------------------------------------------------------------
__global__ __launch_bounds__(1024) void k_epilogue(
    const float* __restrict__ y, const float* __restrict__ qb,
    const unsigned* __restrict__ gmax, const float* __restrict__ c,
    float* __restrict__ out)
{
    __shared__ float sred[17];
    int tid = threadIdx.x;
    float v[4][4];

    // q1 = Q(x@W); yb = q1 + Q(b)
    #pragma unroll
    for (int g = 0; g < 4; ++g) {
        float s = qscale(__uint_as_float(gmax[g]));
        #pragma unroll
        for (int i = 0; i < 4; ++i) {
            int col = i * 1024 + tid;
            v[g][i] = quant1(y[g * 4096 + col], s) + qb[g * 4096 + col];
        }
    }

    // q2 = Q(yb); act = tanh/sigmoid(q2)
    for (int g = 0; g < 4; ++g) {
        float pm = 0.0f;
        #pragma unroll
        for (int i = 0; i < 4; ++i) pm = fmaxf(pm, fabsf(v[g][i]));
        float s = qscale(block_max_red(pm, sred));
        #pragma unroll
        for (int i = 0; i < 4; ++i) {
            float q = quant1(v[g][i], s);
            v[g][i] = (g == 2) ? tanhf(q) : (1.0f / (1.0f + expf(-q)));
        }
    }

    // q3 = Q(act)  -> v[0]=zf, v[1]=zi, v[2]=z, v[3]=zo
    for (int g = 0; g < 4; ++g) {
        float pm = 0.0f;
        #pragma unroll
        for (int i = 0; i < 4; ++i) pm = fmaxf(pm, fabsf(v[g][i]));
        float s = qscale(block_max_red(pm, sred));
        #pragma unroll
        for (int i = 0; i < 4; ++i) v[g][i] = quant1(v[g][i], s);
    }

    // memory = Q(z * zi)
    float mem[4];
    #pragma unroll
    for (int i = 0; i < 4; ++i) mem[i] = v[2][i] * v[1][i];
    quant_vec4(mem, sred);

    // cf = Q(c * zf)
    float cf[4];
    #pragma unroll
    for (int i = 0; i < 4; ++i) cf[i] = c[i * 1024 + tid] * v[0][i];
    quant_vec4(cf, sred);

    // c_new = Q(cf + memory)
    float cn[4];
    #pragma unroll
    for (int i = 0; i < 4; ++i) cn[i] = cf[i] + mem[i];
    quant_vec4(cn, sred);

    // t = Q(tanh(c_new))
    float tc[4];
    #pragma unroll
    for (int i = 0; i < 4; ++i) tc[i] = tanhf(cn[i]);
    quant_vec4(tc, sred);

    // h_new = Q(zo * t)
    float hn[4];
    #pragma unroll
    for (int i = 0; i < 4; ++i) hn[i] = v[3][i] * tc[i];
    quant_vec4(hn, sred);
    #pragma unroll
    for (int i = 0; i < 4; ++i) out[i * 1024 + tid] = hn[i];
}

// ---------------------------------------------------------------------------
extern "C" void kernel_launch(void* const* d_in, const int* in_sizes, int n_in,
                              void* d_out, int out_size, void* d_ws, size_t ws_size,
                              hipStream_t stream) {
    const float* x = (const float*)d_in[0];   // inputs [1,4096]
    const float* c = (const float*)d_in[1];   // c      [1,4096]
    const float* h = (const float*)d_in[2];   // h      [1,4096]
    Ptrs4 wts, bs;
    wts.p[0] = (const float*)d_in[3];  bs.p[0] = (const float*)d_in[4];   // Wf
    wts.p[1] = (const float*)d_in[5];  bs.p[1] = (const float*)d_in[6];   // Wi
    wts.p[2] = (const float*)d_in[7];  bs.p[2] = (const float*)d_in[8];   // Wc
    wts.p[3] = (const float*)d_in[9];  bs.p[3] = (const float*)d_in[10];  // Wo

    float* ws = (float*)d_ws;

    // Primary layout: pbig 4*256*4096 | psmall 4*32*4096 | concat 8192 |
    //                 qb 16384 | yv 16384 | gmax
    const size_t PBIG = 4u * 256u * 4096u;          // 4,194,304 floats
    const size_t PSM  = 4u * 32u * 4096u;           //   524,288 floats
    const size_t NEED = (PBIG + PSM + 8192 + 16384 + 16384 + 16) * sizeof(float);

    if (ws_size >= NEED) {
        float* pbig     = ws;
        float* psmall   = ws + PBIG;
        float* concat_q = ws + PBIG + PSM;
        float* qb       = concat_q + 8192;
        float* yv       = qb + 16384;
        unsigned* gmax  = (unsigned*)(yv + 16384);

        hipLaunchKernelGGL(k_prep,      dim3(5),         dim3(1024), 0, stream,
                           x, h, bs, concat_q, qb, gmax);
        hipLaunchKernelGGL(k_gemv_rows, dim3(256, 4),    dim3(256),  0, stream,
                           wts, concat_q, pbig);
        hipLaunchKernelGGL(k_mid,       dim3(4, 32, 4),  dim3(256),  0, stream,
                           pbig, psmall);
        hipLaunchKernelGGL(k_reduce,    dim3(64),        dim3(256),  0, stream,
                           psmall, yv, gmax);
        hipLaunchKernelGGL(k_epilogue,  dim3(1),         dim3(1024), 0, stream,
                           yv, qb, gmax, c, (float*)d_out);
    } else {
        // Fallback: round-6 layout (2.16 MiB), known-passing.
        float* partials = ws;                        // 4*32*4096
        float* concat_q = ws + 524288;
        float* qb       = ws + 532480;
        float* yv       = ws + 548864;
        unsigned* gmax  = (unsigned*)(ws + 565248);

        hipLaunchKernelGGL(k_prep,     dim3(5),        dim3(1024), 0, stream,
                           x, h, bs, concat_q, qb, gmax);
        hipLaunchKernelGGL(k_gemv_fb,  dim3(8, 32, 4), dim3(256),  0, stream,
                           wts, concat_q, partials);
        hipLaunchKernelGGL(k_reduce,   dim3(64),       dim3(256),  0, stream,
                           partials, yv, gmax);
        hipLaunchKernelGGL(k_epilogue, dim3(1),        dim3(1024), 0, stream,
                           yv, qb, gmax, c, (float*)d_out);
    }
}